// Round 8
// baseline (52.417 us; speedup 1.0000x reference)
//
#include <hip/hip_runtime.h>
#include <cstdint>
#include <cstddef>

typedef int v4i __attribute__((ext_vector_type(4)));

#define QMIN_F (-128.0f)
#define QMAX_F (127.0f)
#define SMALL_THR 6.1e-05f

#define WAITVM(n) asm volatile("s_waitcnt vmcnt(" #n ")" ::: "memory")
#define WAITLGKM0 asm volatile("s_waitcnt lgkmcnt(0)" ::: "memory")

// ---------------------------------------------------------------------------
// Kernel 1: per-row dynamic quantization + fused weight pack (at BW roofline).
// ---------------------------------------------------------------------------
__global__ __launch_bounds__(256) void quant_rows_kernel(
    const float* __restrict__ x, signed char* __restrict__ q,
    float* __restrict__ scales, int* __restrict__ zps, int* __restrict__ sums,
    const int* __restrict__ w32, int* __restrict__ w8pk, int n4, int K) {
  const int gidx = blockIdx.x * 256 + threadIdx.x;
  if (gidx < n4) {
    v4i pv = *(const v4i*)(w32 + gidx * 4);
    w8pk[gidx] = (pv.x & 255) | ((pv.y & 255) << 8) | ((pv.z & 255) << 16) |
                 (pv.w << 24);
  }

  const int wave = threadIdx.x >> 6;
  const int lane = threadIdx.x & 63;
  const int row  = blockIdx.x * 4 + wave;
  const float* xr = x + (size_t)row * K;

  float4 v[4];
  float vmin = 0.0f, vmax = 0.0f, vsum = 0.0f;
#pragma unroll
  for (int j = 0; j < 4; ++j) {
    v[j] = *(const float4*)(xr + j * 256 + lane * 4);
    vmin = fminf(vmin, fminf(fminf(v[j].x, v[j].y), fminf(v[j].z, v[j].w)));
    vmax = fmaxf(vmax, fmaxf(fmaxf(v[j].x, v[j].y), fmaxf(v[j].z, v[j].w)));
    vsum += (v[j].x + v[j].y) + (v[j].z + v[j].w);
  }
#pragma unroll
  for (int off = 32; off >= 1; off >>= 1) {
    vmin = fminf(vmin, __shfl_xor(vmin, off));
    vmax = fmaxf(vmax, __shfl_xor(vmax, off));
    vsum += __shfl_xor(vsum, off);
  }

  float scale = (vmax - vmin) / (QMAX_F - QMIN_F);
  float isinf_f = isinf(1.0f / scale) ? 1.0f : 0.0f;
  if (scale == isinf_f) scale = 0.1f;
  float rmin = vmin, rmax = vmax;
  if (scale < SMALL_THR) {
    float amp = SMALL_THR / scale;
    scale = SMALL_THR;
    rmax *= amp;
    rmin *= amp;
  }
  float rdmin = rmin / scale, rdmax = rmax / scale;
  float err_min = 128.0f + fabsf(rdmin);
  float err_max = 127.0f + fabsf(rdmax);
  float zp0 = (err_min < err_max) ? (QMIN_F - rdmin) : (QMAX_F - rdmax);
  int zp = (int)rintf(zp0);
  if (zp0 < QMIN_F) zp = -128;
  if (zp0 > QMAX_F) zp = 127;
  float inv = 1.0f / scale;

  if (lane == 0) {
    scales[row] = scale;
    zps[row]    = zp;
    sums[row]   = (int)rintf(vsum * inv);
  }

  const float zpf = (float)zp;
  int* qi = (int*)(q + (size_t)row * K);
#pragma unroll
  for (int j = 0; j < 4; ++j) {
    float t0 = fminf(fmaxf(rintf(v[j].x * inv) + zpf, QMIN_F), QMAX_F);
    float t1 = fminf(fmaxf(rintf(v[j].y * inv) + zpf, QMIN_F), QMAX_F);
    float t2 = fminf(fmaxf(rintf(v[j].z * inv) + zpf, QMIN_F), QMAX_F);
    float t3 = fminf(fmaxf(rintf(v[j].w * inv) + zpf, QMIN_F), QMAX_F);
    int pack = ((int)t0 & 255) | (((int)t1 & 255) << 8) |
               (((int)t2 & 255) << 16) | ((int)t3 << 24);
    qi[j * 64 + lane] = pack;
  }
}

// ---------------------------------------------------------------------------
// Kernel 2: int8 GEMM + fused dequant. BM=128, BN=64, BK=64, 4 waves (2x2,
// 64x32 out each, acc=32 VGPR). LDS 24 KB (2 x (A 8K + B 4K)) => 5 blocks/CU
// = 20 waves/CU TLP; grid 2048 = 8 blocks/CU => staggered retirement spreads
// output stores across the kernel (no monolithic tail). Counted vmcnt
// (WAITVM(3)); raw s_barrier + lgkmcnt(0). Swizzle slot' = slot^((row>>1)&3)
// on gload source AND ds_read (R6: conflicts == 0). Plain stores (R6: nt
// stores caused 1.5x write amplification).
// ---------------------------------------------------------------------------
__device__ __forceinline__ void gload_lds16(const void* g, void* l) {
  __builtin_amdgcn_global_load_lds(
      (const __attribute__((address_space(1))) void*)g,
      (__attribute__((address_space(3))) void*)l, 16, 0, 0);
}

__device__ __forceinline__ void stage_tile(
    const signed char* __restrict__ q, const signed char* __restrict__ w,
    char* buf, int rowA0, int rowB0, int k0, int K, int tid) {
#pragma unroll
  for (int i = 0; i < 2; ++i) {   // A: 512 chunks of 16B (128 rows x 4 slots)
    int c  = (i << 8) + tid;
    int r  = c >> 2;
    int sl = (c & 3) ^ ((r >> 1) & 3);
    gload_lds16(q + (size_t)(rowA0 + r) * K + k0 + (sl << 4), buf + (c << 4));
  }
  {                               // B: 256 chunks (64 rows x 4 slots)
    int c  = tid;
    int r  = c >> 2;
    int sl = (c & 3) ^ ((r >> 1) & 3);
    gload_lds16(w + (size_t)(rowB0 + r) * K + k0 + (sl << 4),
                buf + 8192 + (c << 4));
  }
}

__global__ __launch_bounds__(256, 5) void gemm_dequant_kernel(
    const signed char* __restrict__ q, const signed char* __restrict__ w,
    const float* __restrict__ scales, const int* __restrict__ zps,
    const int* __restrict__ sums, const float* __restrict__ bias,
    const float* __restrict__ w_scales, const int* __restrict__ w_zeros,
    const int* __restrict__ w_sums, float* __restrict__ out,
    int N, int K, int nblk) {
  __shared__ char sh[2][12288];              // per buffer: A 8K | B 4K
  const int tid  = threadIdx.x;
  const int lane = tid & 63;
  const int wave = tid >> 6;
  const int wr = wave >> 1;                  // 0..1 (M half: 64 rows)
  const int wc = wave & 1;                   // 0..1 (N half: 32 cols)
  const int fr = lane & 15;
  const int kb = lane >> 4;                  // 16B K-slot 0..3
  const int ntN = N >> 6;                    // 16
  // XCD-chunked swizzle: 256 consecutive lins per XCD = 16 tileM x 16 tileN
  // -> A 2MB + w 1MB fit the 4MB per-XCD L2.
  const int per = nblk >> 3;
  const int lin = ((int)blockIdx.x & 7) * per + ((int)blockIdx.x >> 3);
  const int rowA0 = (lin / ntN) << 7;        // BM=128
  const int rowB0 = (lin % ntN) << 6;        // BN=64
  const int wrbase = wr << 6;                // 0 or 64
  const int wcbase = wc << 5;                // 0 or 32

  v4i acc[4][2];
#pragma unroll
  for (int i = 0; i < 4; ++i)
#pragma unroll
    for (int j = 0; j < 2; ++j) {
      v4i z = {0, 0, 0, 0};
      acc[i][j] = z;
    }

  const int NT = K >> 6;                     // 16 K-tiles
  stage_tile(q, w, sh[0], rowA0, rowB0, 0, K, tid);

  for (int t = 0; t < NT; ++t) {
    if (t + 1 < NT) {
      stage_tile(q, w, sh[(t + 1) & 1], rowA0, rowB0, (t + 1) << 6, K, tid);
      WAITVM(3);                             // tile t's 3 loads done; t+1's fly
    } else {
      WAITVM(0);
    }
    __builtin_amdgcn_s_barrier();            // tile t staged & visible

    const char* bA = sh[t & 1];
    const char* bB = bA + 8192;

    v4i afrag[4], bfrag[2];
#pragma unroll
    for (int n = 0; n < 2; ++n) {
      int rb = wcbase + (n << 4) + fr;
      bfrag[n] = *(const v4i*)(bB + (rb << 6) + ((kb ^ ((rb >> 1) & 3)) << 4));
    }
#pragma unroll
    for (int m = 0; m < 4; ++m) {
      int ra = wrbase + (m << 4) + fr;
      afrag[m] = *(const v4i*)(bA + (ra << 6) + ((kb ^ ((ra >> 1) & 3)) << 4));
    }
    WAITLGKM0;
    __builtin_amdgcn_s_barrier();            // LDS reads drained: buffer free

    __builtin_amdgcn_s_setprio(1);
#pragma unroll
    for (int m = 0; m < 4; ++m)
#pragma unroll
      for (int n = 0; n < 2; ++n)
        acc[m][n] = __builtin_amdgcn_mfma_i32_16x16x64_i8(afrag[m], bfrag[n],
                                                          acc[m][n], 0, 0, 0);
    __builtin_amdgcn_s_setprio(0);
  }

  // Epilogue: C/D layout col = lane&15, row = (lane>>4)*4 + reg.
  const int baseM = rowA0 + wrbase;
  const int baseN = rowB0 + wcbase;
  const int qr = (lane >> 4) << 2;
  const int qc = lane & 15;
  float cb[2], cwsc[2];
  int cwz[2], cws[2];
#pragma unroll
  for (int n = 0; n < 2; ++n) {
    int col = baseN + (n << 4) + qc;
    cb[n]   = bias[col];
    cwsc[n] = w_scales[col];
    cwz[n]  = w_zeros[col];
    cws[n]  = w_sums[col];
  }
#pragma unroll
  for (int i = 0; i < 4; ++i) {
    const int m0 = baseM + (i << 4) + qr;
    float sc[4];
    int zp4[4], sm4[4];
#pragma unroll
    for (int j = 0; j < 4; ++j) {
      sc[j]  = scales[m0 + j];
      zp4[j] = zps[m0 + j];
      sm4[j] = sums[m0 + j];
    }
#pragma unroll
    for (int n = 0; n < 2; ++n) {
      const int col = baseN + (n << 4) + qc;
#pragma unroll
      for (int j = 0; j < 4; ++j) {
        int d    = acc[i][n][j];
        int temp = zp4[j] * cws[n] + sm4[j] * cwz[n];
        out[(size_t)(m0 + j) * N + col] =
            cb[n] + (float)(d - temp) * (sc[j] * cwsc[n]);
      }
    }
  }
}

extern "C" void kernel_launch(void* const* d_in, const int* in_sizes, int n_in,
                              void* d_out, int out_size, void* d_ws, size_t ws_size,
                              hipStream_t stream) {
  const float* inp      = (const float*)d_in[0];
  const int*   qw32     = (const int*)d_in[1];   // int8 in ref -> int32 on device
  const float* bias     = (const float*)d_in[2];
  const float* w_scales = (const float*)d_in[3];
  const int*   w_zeros  = (const int*)d_in[4];
  const int*   w_sums   = (const int*)d_in[5];

  const int N = in_sizes[2];      // 1024
  const int K = in_sizes[1] / N;  // 1024
  const int M = in_sizes[0] / K;  // 16384

  float*       scales = (float*)d_ws;
  int*         zps    = (int*)((char*)d_ws + (size_t)M * 4);
  int*         sums   = (int*)((char*)d_ws + (size_t)M * 8);
  signed char* q      = (signed char*)((char*)d_ws + (size_t)M * 12);
  signed char* w8     = (signed char*)((char*)d_ws + (size_t)M * 12 + (size_t)M * K);

  const int n4 = (N * K) / 4;
  const int nblk = (M / 128) * (N / 64);     // 2048 blocks = 8/CU dispatched
  quant_rows_kernel<<<M / 4, 256, 0, stream>>>(inp, q, scales, zps, sums,
                                               qw32, (int*)w8, n4, K);
  gemm_dequant_kernel<<<nblk, 256, 0, stream>>>(
      q, w8, scales, zps, sums, bias, w_scales, w_zeros, w_sums,
      (float*)d_out, N, K, nblk);
}

// Round 9
// 47.323 us; speedup vs baseline: 1.1076x; 1.1076x over previous
//
#include <hip/hip_runtime.h>
#include <cstdint>
#include <cstddef>

typedef int v4i __attribute__((ext_vector_type(4)));

#define QMIN_F (-128.0f)
#define QMAX_F (127.0f)
#define SMALL_THR 6.1e-05f

#define WAITVM(n) asm volatile("s_waitcnt vmcnt(" #n ")" ::: "memory")
#define WAITLGKM0 asm volatile("s_waitcnt lgkmcnt(0)" ::: "memory")

// ---------------------------------------------------------------------------
// Kernel 1: per-row dynamic quantization + fused weight pack (at BW roofline).
// ---------------------------------------------------------------------------
__global__ __launch_bounds__(256) void quant_rows_kernel(
    const float* __restrict__ x, signed char* __restrict__ q,
    float* __restrict__ scales, int* __restrict__ zps, int* __restrict__ sums,
    const int* __restrict__ w32, int* __restrict__ w8pk, int n4, int K) {
  const int gidx = blockIdx.x * 256 + threadIdx.x;
  if (gidx < n4) {
    v4i pv = *(const v4i*)(w32 + gidx * 4);
    w8pk[gidx] = (pv.x & 255) | ((pv.y & 255) << 8) | ((pv.z & 255) << 16) |
                 (pv.w << 24);
  }

  const int wave = threadIdx.x >> 6;
  const int lane = threadIdx.x & 63;
  const int row  = blockIdx.x * 4 + wave;
  const float* xr = x + (size_t)row * K;

  float4 v[4];
  float vmin = 0.0f, vmax = 0.0f, vsum = 0.0f;
#pragma unroll
  for (int j = 0; j < 4; ++j) {
    v[j] = *(const float4*)(xr + j * 256 + lane * 4);
    vmin = fminf(vmin, fminf(fminf(v[j].x, v[j].y), fminf(v[j].z, v[j].w)));
    vmax = fmaxf(vmax, fmaxf(fmaxf(v[j].x, v[j].y), fmaxf(v[j].z, v[j].w)));
    vsum += (v[j].x + v[j].y) + (v[j].z + v[j].w);
  }
#pragma unroll
  for (int off = 32; off >= 1; off >>= 1) {
    vmin = fminf(vmin, __shfl_xor(vmin, off));
    vmax = fmaxf(vmax, __shfl_xor(vmax, off));
    vsum += __shfl_xor(vsum, off);
  }

  float scale = (vmax - vmin) / (QMAX_F - QMIN_F);
  float isinf_f = isinf(1.0f / scale) ? 1.0f : 0.0f;
  if (scale == isinf_f) scale = 0.1f;
  float rmin = vmin, rmax = vmax;
  if (scale < SMALL_THR) {
    float amp = SMALL_THR / scale;
    scale = SMALL_THR;
    rmax *= amp;
    rmin *= amp;
  }
  float rdmin = rmin / scale, rdmax = rmax / scale;
  float err_min = 128.0f + fabsf(rdmin);
  float err_max = 127.0f + fabsf(rdmax);
  float zp0 = (err_min < err_max) ? (QMIN_F - rdmin) : (QMAX_F - rdmax);
  int zp = (int)rintf(zp0);
  if (zp0 < QMIN_F) zp = -128;
  if (zp0 > QMAX_F) zp = 127;
  float inv = 1.0f / scale;

  if (lane == 0) {
    scales[row] = scale;
    zps[row]    = zp;
    sums[row]   = (int)rintf(vsum * inv);
  }

  const float zpf = (float)zp;
  int* qi = (int*)(q + (size_t)row * K);
#pragma unroll
  for (int j = 0; j < 4; ++j) {
    float t0 = fminf(fmaxf(rintf(v[j].x * inv) + zpf, QMIN_F), QMAX_F);
    float t1 = fminf(fmaxf(rintf(v[j].y * inv) + zpf, QMIN_F), QMAX_F);
    float t2 = fminf(fmaxf(rintf(v[j].z * inv) + zpf, QMIN_F), QMAX_F);
    float t3 = fminf(fmaxf(rintf(v[j].w * inv) + zpf, QMIN_F), QMAX_F);
    int pack = ((int)t0 & 255) | (((int)t1 & 255) << 8) |
               (((int)t2 & 255) << 16) | ((int)t3 << 24);
    qi[j * 64 + lane] = pack;
  }
}

// ---------------------------------------------------------------------------
// Kernel 2: int8 GEMM + fused dequant. BM=256, BN=128, BK=64, 4 waves
// (2M x 2N), per-wave output 128x64 (acc = 32 v4i = 128 VGPR).
// Rationale (R8 post-mortem): LDS reads scale as M*N*K*(1/Wm+1/Wn);
// wave-out 128x64 cuts reads 512->384 MB and staging 256->192 MB vs R7,
// and halves barrier events (512 blocks x 16 steps). 2-buffer LDS 48 KB,
// 2 blocks/CU (grid 512 = exact fill). Counted WAITVM(6); raw s_barrier +
// lgkmcnt(0); conflict-free slot^((row>>1)&3) swizzle both sides (R6:
// conflicts==0); plain stores (R6: nt = 1.5x write amplification).
// ---------------------------------------------------------------------------
__device__ __forceinline__ void gload_lds16(const void* g, void* l) {
  __builtin_amdgcn_global_load_lds(
      (const __attribute__((address_space(1))) void*)g,
      (__attribute__((address_space(3))) void*)l, 16, 0, 0);
}

#define BUFA_SZ 16384   // 256 rows x 64 B
#define BUFB_SZ 8192    // 128 rows x 64 B

__device__ __forceinline__ void stage_tile(
    const signed char* __restrict__ q, const signed char* __restrict__ w,
    char* buf, int rowA0, int rowB0, int k0, int K, int tid) {
#pragma unroll
  for (int i = 0; i < 4; ++i) {   // A: 1024 chunks of 16B (256 rows x 4 slots)
    int c  = (i << 8) + tid;
    int r  = c >> 2;
    int sl = (c & 3) ^ ((r >> 1) & 3);
    gload_lds16(q + (size_t)(rowA0 + r) * K + k0 + (sl << 4), buf + (c << 4));
  }
#pragma unroll
  for (int i = 0; i < 2; ++i) {   // B: 512 chunks (128 rows x 4 slots)
    int c  = (i << 8) + tid;
    int r  = c >> 2;
    int sl = (c & 3) ^ ((r >> 1) & 3);
    gload_lds16(w + (size_t)(rowB0 + r) * K + k0 + (sl << 4),
                buf + BUFA_SZ + (c << 4));
  }
}

__global__ __launch_bounds__(256, 2) void gemm_dequant_kernel(
    const signed char* __restrict__ q, const signed char* __restrict__ w,
    const float* __restrict__ scales, const int* __restrict__ zps,
    const int* __restrict__ sums, const float* __restrict__ bias,
    const float* __restrict__ w_scales, const int* __restrict__ w_zeros,
    const int* __restrict__ w_sums, float* __restrict__ out,
    int N, int K, int nblk) {
  __shared__ char sh[2][BUFA_SZ + BUFB_SZ];  // 48 KB
  const int tid  = threadIdx.x;
  const int lane = tid & 63;
  const int wave = tid >> 6;
  const int wr = wave >> 1;                  // 0..1: M half (128 rows)
  const int wc = wave & 1;                   // 0..1: N half (64 cols)
  const int fr = lane & 15;
  const int kb = lane >> 4;                  // 16B K-slot 0..3
  const int ntN = N >> 7;                    // 8
  // XCD-chunked swizzle: 64 consecutive lins per XCD = 8 tileM x 8 tileN
  // -> A 8 panels x 256 KB = 2 MB + w 1 MB fit the 4 MB per-XCD L2.
  const int per = nblk >> 3;
  const int lin = ((int)blockIdx.x & 7) * per + ((int)blockIdx.x >> 3);
  const int rowA0 = (lin / ntN) << 8;        // BM=256
  const int rowB0 = (lin % ntN) << 7;        // BN=128
  const int wrbase = wr << 7;                // 0 or 128
  const int wcbase = wc << 6;                // 0 or 64

  v4i acc[8][4];
#pragma unroll
  for (int i = 0; i < 8; ++i)
#pragma unroll
    for (int j = 0; j < 4; ++j) {
      v4i z = {0, 0, 0, 0};
      acc[i][j] = z;
    }

  const int NT = K >> 6;                     // 16 K-tiles
  stage_tile(q, w, sh[0], rowA0, rowB0, 0, K, tid);

  for (int t = 0; t < NT; ++t) {
    if (t + 1 < NT) {
      stage_tile(q, w, sh[(t + 1) & 1], rowA0, rowB0, (t + 1) << 6, K, tid);
      WAITVM(6);                             // tile t's 6 loads done; t+1's fly
    } else {
      WAITVM(0);
    }
    __builtin_amdgcn_s_barrier();            // tile t staged & visible

    const char* bA = sh[t & 1];
    const char* bB = bA + BUFA_SZ;

    v4i afrag[8], bfrag[4];
#pragma unroll
    for (int n = 0; n < 4; ++n) {
      int rb = wcbase + (n << 4) + fr;
      bfrag[n] = *(const v4i*)(bB + (rb << 6) + ((kb ^ ((rb >> 1) & 3)) << 4));
    }
#pragma unroll
    for (int m = 0; m < 8; ++m) {
      int ra = wrbase + (m << 4) + fr;
      afrag[m] = *(const v4i*)(bA + (ra << 6) + ((kb ^ ((ra >> 1) & 3)) << 4));
    }
    WAITLGKM0;
    __builtin_amdgcn_s_barrier();            // LDS reads drained: buffer free

    __builtin_amdgcn_s_setprio(1);
#pragma unroll
    for (int m = 0; m < 8; ++m)
#pragma unroll
      for (int n = 0; n < 4; ++n)
        acc[m][n] = __builtin_amdgcn_mfma_i32_16x16x64_i8(afrag[m], bfrag[n],
                                                          acc[m][n], 0, 0, 0);
    __builtin_amdgcn_s_setprio(0);
  }

  // Epilogue: C/D layout col = lane&15, row = (lane>>4)*4 + reg.
  const int baseM = rowA0 + wrbase;
  const int baseN = rowB0 + wcbase;
  const int qr = (lane >> 4) << 2;
  const int qc = lane & 15;
  float cb[4], cwsc[4];
  int cwz[4], cws[4];
#pragma unroll
  for (int n = 0; n < 4; ++n) {
    int col = baseN + (n << 4) + qc;
    cb[n]   = bias[col];
    cwsc[n] = w_scales[col];
    cwz[n]  = w_zeros[col];
    cws[n]  = w_sums[col];
  }
#pragma unroll
  for (int i = 0; i < 8; ++i) {
    const int m0 = baseM + (i << 4) + qr;
    float sc[4];
    int zp4[4], sm4[4];
#pragma unroll
    for (int j = 0; j < 4; ++j) {
      sc[j]  = scales[m0 + j];
      zp4[j] = zps[m0 + j];
      sm4[j] = sums[m0 + j];
    }
#pragma unroll
    for (int n = 0; n < 4; ++n) {
      const int col = baseN + (n << 4) + qc;
#pragma unroll
      for (int j = 0; j < 4; ++j) {
        int d    = acc[i][n][j];
        int temp = zp4[j] * cws[n] + sm4[j] * cwz[n];
        out[(size_t)(m0 + j) * N + col] =
            cb[n] + (float)(d - temp) * (sc[j] * cwsc[n]);
      }
    }
  }
}

extern "C" void kernel_launch(void* const* d_in, const int* in_sizes, int n_in,
                              void* d_out, int out_size, void* d_ws, size_t ws_size,
                              hipStream_t stream) {
  const float* inp      = (const float*)d_in[0];
  const int*   qw32     = (const int*)d_in[1];   // int8 in ref -> int32 on device
  const float* bias     = (const float*)d_in[2];
  const float* w_scales = (const float*)d_in[3];
  const int*   w_zeros  = (const int*)d_in[4];
  const int*   w_sums   = (const int*)d_in[5];

  const int N = in_sizes[2];      // 1024
  const int K = in_sizes[1] / N;  // 1024
  const int M = in_sizes[0] / K;  // 16384

  float*       scales = (float*)d_ws;
  int*         zps    = (int*)((char*)d_ws + (size_t)M * 4);
  int*         sums   = (int*)((char*)d_ws + (size_t)M * 8);
  signed char* q      = (signed char*)((char*)d_ws + (size_t)M * 12);
  signed char* w8     = (signed char*)((char*)d_ws + (size_t)M * 12 + (size_t)M * K);

  const int n4 = (N * K) / 4;
  const int nblk = (M / 256) * (N / 128);    // 512 blocks = 2/CU exact fill
  quant_rows_kernel<<<M / 4, 256, 0, stream>>>(inp, q, scales, zps, sums,
                                               qw32, (int*)w8, n4, K);
  gemm_dequant_kernel<<<nblk, 256, 0, stream>>>(
      q, w8, scales, zps, sums, bias, w_scales, w_zeros, w_sums,
      (float*)d_out, N, K, nblk);
}